// Round 2
// baseline (528.226 us; speedup 1.0000x reference)
//
#include <hip/hip_runtime.h>

#define EE 512
#define HH 256
#define QQ 1024
#define SS 512
#define NSTEPS 3

// C[M][N] = act(X[M][K] @ W[K][N] + bias); all f32.
// BM=BN=64, BK=32, 256 threads, 4x4 register tile per thread.
// Requires: M%64==0, N%64==0, K%32==0.
__global__ __launch_bounds__(256) void gemm_k(const float* __restrict__ X,
                                              const float* __restrict__ W,
                                              const float* __restrict__ bias,
                                              float* __restrict__ C,
                                              int M, int N, int K, int relu) {
    __shared__ float Xs[64][33];
    __shared__ float Ws[32][64];
    const int tid = threadIdx.x;
    const int tx = tid & 15;          // n group (cols n0 + 4*tx .. +3)
    const int ty = tid >> 4;          // m group (rows m0 + ty + 16*im)
    const int m0 = blockIdx.y << 6;
    const int n0 = blockIdx.x << 6;
    const int r  = tid >> 3;          // 0..31
    const int c4 = (tid & 7) << 2;    // X tile col
    const int c8 = (tid & 7) << 3;    // W tile col
    float acc[4][4] = {{0.f,0.f,0.f,0.f},{0.f,0.f,0.f,0.f},
                       {0.f,0.f,0.f,0.f},{0.f,0.f,0.f,0.f}};

    for (int k0 = 0; k0 < K; k0 += 32) {
        float4 v0 = *(const float4*)&X[(m0 + r) * K + k0 + c4];
        float4 v1 = *(const float4*)&X[(m0 + r + 32) * K + k0 + c4];
        float4 w0 = *(const float4*)&W[(k0 + r) * N + n0 + c8];
        float4 w1 = *(const float4*)&W[(k0 + r) * N + n0 + c8 + 4];
        Xs[r][c4+0] = v0.x; Xs[r][c4+1] = v0.y; Xs[r][c4+2] = v0.z; Xs[r][c4+3] = v0.w;
        Xs[r+32][c4+0] = v1.x; Xs[r+32][c4+1] = v1.y; Xs[r+32][c4+2] = v1.z; Xs[r+32][c4+3] = v1.w;
        *(float4*)&Ws[r][c8]     = w0;
        *(float4*)&Ws[r][c8 + 4] = w1;
        __syncthreads();
        #pragma unroll
        for (int kk = 0; kk < 32; kk++) {
            float4 b = *(const float4*)&Ws[kk][tx << 2];
            float a0 = Xs[ty][kk];
            float a1 = Xs[ty + 16][kk];
            float a2 = Xs[ty + 32][kk];
            float a3 = Xs[ty + 48][kk];
            acc[0][0] += a0*b.x; acc[0][1] += a0*b.y; acc[0][2] += a0*b.z; acc[0][3] += a0*b.w;
            acc[1][0] += a1*b.x; acc[1][1] += a1*b.y; acc[1][2] += a1*b.z; acc[1][3] += a1*b.w;
            acc[2][0] += a2*b.x; acc[2][1] += a2*b.y; acc[2][2] += a2*b.z; acc[2][3] += a2*b.w;
            acc[3][0] += a3*b.x; acc[3][1] += a3*b.y; acc[3][2] += a3*b.z; acc[3][3] += a3*b.w;
        }
        __syncthreads();
    }

    float bx = 0.f, by = 0.f, bz = 0.f, bw = 0.f;
    if (bias) {
        bx = bias[n0 + (tx<<2) + 0];
        by = bias[n0 + (tx<<2) + 1];
        bz = bias[n0 + (tx<<2) + 2];
        bw = bias[n0 + (tx<<2) + 3];
    }
    #pragma unroll
    for (int im = 0; im < 4; im++) {
        int m = m0 + ty + (im << 4);
        float4 o;
        o.x = acc[im][0] + bx; o.y = acc[im][1] + by;
        o.z = acc[im][2] + bz; o.w = acc[im][3] + bw;
        if (relu) {
            o.x = fmaxf(o.x, 0.f); o.y = fmaxf(o.y, 0.f);
            o.z = fmaxf(o.z, 0.f); o.w = fmaxf(o.w, 0.f);
        }
        *(float4*)&C[m * N + n0 + (tx << 2)] = o;
    }
}

// cnt_i = #{ j : y_j == y_i } - 1 ; invden_i = 1/max(cnt_i, 1)
__global__ __launch_bounds__(512) void cnt_k(const int* __restrict__ y,
                                             float* __restrict__ cntf,
                                             float* __restrict__ invden) {
    __shared__ int ys[SS];
    int t = threadIdx.x;
    ys[t] = y[t];
    __syncthreads();
    int yi = ys[t];
    int c = 0;
    for (int j = 0; j < SS; j++) c += (ys[j] == yi) ? 1 : 0;
    c -= 1;  // remove self
    cntf[t]  = (float)c;
    invden[t] = 1.f / fmaxf((float)c, 1.f);
}

// hsum[i][h] = sum_{j: y_j==y_i, j!=i} relu(A[i][h] + B[j][h] + bm1t[h])
// grid: S blocks (one per i), 256 threads (one per h). Class test is
// block-uniform -> cheap skip of non-matching j.
__global__ __launch_bounds__(256) void hsum_k(const float* __restrict__ A,
                                              const float* __restrict__ B,
                                              const int* __restrict__ y,
                                              const float* __restrict__ bm1t,
                                              float* __restrict__ hsum) {
    __shared__ int ys[SS];
    const int i = blockIdx.x;
    const int h = threadIdx.x;
    ys[h] = y[h];
    ys[h + 256] = y[h + 256];
    __syncthreads();
    const int yi = ys[i];
    const float a = A[i * HH + h] + bm1t[h];
    float acc = 0.f;
    for (int j = 0; j < SS; j++) {
        if (ys[j] == yi) {
            float v = a + B[j * HH + h];
            acc += fmaxf(v, 0.f);
        }
    }
    // loop included j == i (same class by definition): subtract self term
    acc -= fmaxf(a + B[i * HH + h], 0.f);
    hsum[i * HH + h] = acc;
}

// s[i][h] += (G[i][h] + cnt_i * bm2t[h]) * invden_i
__global__ __launch_bounds__(256) void agg_k(float* __restrict__ s,
                                             const float* __restrict__ G,
                                             const float* __restrict__ cntf,
                                             const float* __restrict__ invden,
                                             const float* __restrict__ bm2t) {
    int idx = blockIdx.x * 256 + threadIdx.x;
    int i = idx >> 8, h = idx & 255;
    s[idx] += (G[idx] + cntf[i] * bm2t[h]) * invden[i];
}

// hsT[h][j] = hs[j][h]   (S x H -> H x S)
__global__ __launch_bounds__(256) void transpose_k(const float* __restrict__ hs,
                                                   float* __restrict__ hsT) {
    int idx = blockIdx.x * 256 + threadIdx.x;   // over S*H, coalesced read
    int j = idx >> 8, h = idx & 255;
    hsT[h * SS + j] = hs[idx];
}

// scores[i][j] = sum_h relu(hq[i][h] + hsT[h][j]) * wr2[h] + br2
// (br1 already folded into hs). grid (Q/8, S/256), 256 threads; 8 i-rows/block.
__global__ __launch_bounds__(256) void scores_k(const float* __restrict__ hq,
                                                const float* __restrict__ hsT,
                                                const float* __restrict__ wr2,
                                                const float* __restrict__ br2,
                                                float* __restrict__ out) {
    __shared__ float hqs[8][HH];
    __shared__ float w2s[HH];
    const int tid = threadIdx.x;
    const int i0 = blockIdx.x << 3;
    const int j  = (blockIdx.y << 8) + tid;
    w2s[tid] = wr2[tid];
    #pragma unroll
    for (int ii = 0; ii < 8; ii++) hqs[ii][tid] = hq[(i0 + ii) * HH + tid];
    __syncthreads();
    float acc[8] = {0.f,0.f,0.f,0.f,0.f,0.f,0.f,0.f};
    #pragma unroll 4
    for (int h = 0; h < HH; h++) {
        float v = hsT[h * SS + j];
        float w = w2s[h];
        #pragma unroll
        for (int ii = 0; ii < 8; ii++) {
            float t = v + hqs[ii][h];
            acc[ii] += fmaxf(t, 0.f) * w;
        }
    }
    float b2 = br2[0];
    #pragma unroll
    for (int ii = 0; ii < 8; ii++)
        out[(i0 + ii) * SS + j] = acc[ii] + b2;
}

extern "C" void kernel_launch(void* const* d_in, const int* in_sizes, int n_in,
                              void* d_out, int out_size, void* d_ws, size_t ws_size,
                              hipStream_t stream) {
    const float* qf  = (const float*)d_in[0];
    const float* sf  = (const float*)d_in[1];
    const int*   y   = (const int*)d_in[2];
    const float* Wn1 = (const float*)d_in[3];
    const float* bn1 = (const float*)d_in[4];
    const float* Wn2 = (const float*)d_in[5];
    const float* bn2 = (const float*)d_in[6];
    const float* Wm1 = (const float*)d_in[7];
    const float* bm1 = (const float*)d_in[8];
    const float* Wm2 = (const float*)d_in[9];
    const float* bm2 = (const float*)d_in[10];
    const float* Wr1 = (const float*)d_in[11];
    const float* br1 = (const float*)d_in[12];
    const float* wr2 = (const float*)d_in[13];
    const float* br2 = (const float*)d_in[14];
    float* out = (float*)d_out;

    float* F    = (float*)d_ws;
    float* X1   = F + 0;             // 1536*256 = 393216  (encoder hidden; dead after layer 2)
    float* QS   = F + 393216;        // 1536*256           (q rows 0..1023, s rows 1024..1535)
    float* q    = QS;
    float* s    = QS + QQ * HH;
    float* A    = F + 786432;        // 512*256
    float* Bm   = F + 917504;        // 512*256
    float* hsum = F + 1048576;       // 512*256
    float* G    = F + 1179648;       // 512*256
    float* hq   = F + 0;             // 1024*256 (reuses dead X1: 0..262144)
    float* hsT  = F + 262144;        // 256*512  (262144..393216, still inside dead X1)
    float* cntf = F + 1310720;       // 512
    float* invd = F + 1311232;       // 512

    // ---- encoder: layer 1 reads inputs directly (q then s) into one batch ----
    gemm_k<<<dim3(4, 16), 256, 0, stream>>>(qf, Wn1, bn1, X1,             QQ, HH, EE, 1);
    gemm_k<<<dim3(4, 8),  256, 0, stream>>>(sf, Wn1, bn1, X1 + QQ * HH,   SS, HH, EE, 1);
    gemm_k<<<dim3(4, 24), 256, 0, stream>>>(X1, Wn2, bn2, QS,           1536, HH, HH, 0);

    // ---- mask statistics ----
    cnt_k<<<1, 512, 0, stream>>>(y, cntf, invd);

    // ---- message-passing steps (factorized: masked sum BEFORE the Wm2 matmul) ----
    for (int t = 0; t < NSTEPS; t++) {
        const float* W1a = Wm1 + t * 2 * HH * HH;
        const float* W1b = W1a + HH * HH;
        const float* b1t = bm1 + t * HH;
        const float* W2t = Wm2 + t * HH * HH;
        const float* b2t = bm2 + t * HH;
        gemm_k<<<dim3(4, 8), 256, 0, stream>>>(s, W1a, nullptr, A,  SS, HH, HH, 0);
        gemm_k<<<dim3(4, 8), 256, 0, stream>>>(s, W1b, nullptr, Bm, SS, HH, HH, 0);
        hsum_k<<<SS, 256, 0, stream>>>(A, Bm, y, b1t, hsum);
        gemm_k<<<dim3(4, 8), 256, 0, stream>>>(hsum, W2t, nullptr, G, SS, HH, HH, 0);
        agg_k<<<512, 256, 0, stream>>>(s, G, cntf, invd, b2t);
    }

    // ---- relation head ----
    gemm_k<<<dim3(4, 16), 256, 0, stream>>>(q, Wr1,           nullptr, hq, QQ, HH, HH, 0);
    gemm_k<<<dim3(4, 8),  256, 0, stream>>>(s, Wr1 + HH * HH, br1,     A,  SS, HH, HH, 0); // hs (+br1)
    transpose_k<<<512, 256, 0, stream>>>(A, hsT);
    scores_k<<<dim3(QQ / 8, SS / 256), 256, 0, stream>>>(hq, hsT, wr2, br2, out);
}

// Round 4
// 237.309 us; speedup vs baseline: 2.2259x; 2.2259x over previous
//
#include <hip/hip_runtime.h>

#define EE 512
#define HH 256
#define QQ 1024
#define SS 512
#define NSTEPS 3

// ---------------------------------------------------------------------------
// Common 32x64 GEMM tile engine: 256 threads, BK=32, register-prefetch
// double buffering. acc[2][4]: rows (ty, ty+16), cols n0 + 4*tx .. +3.
// Xs[32][36] (pad keeps float4 alignment + spreads banks), Ws[32][68].
// ---------------------------------------------------------------------------
#define GEMM_SHARED __shared__ float Xs[32][36]; __shared__ float Ws[32][68]

__device__ __forceinline__ void mm_tile(const float* __restrict__ Xrow, int K,
                                        const float* __restrict__ Wcol, int N,
                                        float (*Xs)[36], float (*Ws)[68],
                                        float acc[2][4]) {
    const int tid = threadIdx.x;
    const int r  = tid >> 3;
    const int c4 = (tid & 7) << 2;
    const int c8 = (tid & 7) << 3;
    const int tx = tid & 15;
    const int ty = tid >> 4;

    float4 vx  = *(const float4*)&Xrow[r * K + c4];
    float4 vw0 = *(const float4*)&Wcol[r * N + c8];
    float4 vw1 = *(const float4*)&Wcol[r * N + c8 + 4];

    for (int k0 = 0; k0 < K; k0 += 32) {
        *(float4*)&Xs[r][c4]     = vx;
        *(float4*)&Ws[r][c8]     = vw0;
        *(float4*)&Ws[r][c8 + 4] = vw1;
        __syncthreads();
        if (k0 + 32 < K) {   // prefetch next K-tile while FMAs run
            vx  = *(const float4*)&Xrow[r * K + k0 + 32 + c4];
            vw0 = *(const float4*)&Wcol[(k0 + 32 + r) * N + c8];
            vw1 = *(const float4*)&Wcol[(k0 + 32 + r) * N + c8 + 4];
        }
        #pragma unroll
        for (int kk = 0; kk < 32; kk++) {
            float4 b = *(const float4*)&Ws[kk][tx << 2];
            float a0 = Xs[ty][kk];
            float a1 = Xs[ty + 16][kk];
            acc[0][0] += a0 * b.x; acc[0][1] += a0 * b.y;
            acc[0][2] += a0 * b.z; acc[0][3] += a0 * b.w;
            acc[1][0] += a1 * b.x; acc[1][1] += a1 * b.y;
            acc[1][2] += a1 * b.z; acc[1][3] += a1 * b.w;
        }
        __syncthreads();
    }
}

// ---------------------------------------------------------------------------
// enc1: [q;s] @ Wn1 + bn1, relu -> X1 (1536 x 256). K=512.
// grid (4, 49): by==48 is the mask-statistics block (class lists, counts).
// ---------------------------------------------------------------------------
__global__ __launch_bounds__(256) void enc1_k(const float* __restrict__ qf,
                                              const float* __restrict__ sf,
                                              const float* __restrict__ Wn1,
                                              const float* __restrict__ bn1,
                                              float* __restrict__ X1,
                                              const int* __restrict__ y,
                                              float* __restrict__ cntf,
                                              float* __restrict__ invd,
                                              int* __restrict__ cls_cnt,
                                              int* __restrict__ cls_list) {
    GEMM_SHARED;
    const int tid = threadIdx.x;
    if (blockIdx.y == 48) {                  // mask statistics
        if (blockIdx.x != 0) return;
        __shared__ int lc[16];
        if (tid < 16) lc[tid] = 0;
        __syncthreads();
        for (int i = tid; i < SS; i += 256) {
            int c = y[i];
            int slot = atomicAdd(&lc[c], 1);
            cls_list[c * SS + slot] = i;
        }
        __syncthreads();
        if (tid < 16) cls_cnt[tid] = lc[tid];
        for (int i = tid; i < SS; i += 256) {
            float n = (float)(lc[y[i]] - 1);
            cntf[i] = n;
            invd[i] = 1.f / fmaxf(n, 1.f);
        }
        return;
    }
    const int m0 = blockIdx.y << 5;
    const int n0 = blockIdx.x << 6;
    const float* Xrow = (m0 < QQ) ? (qf + m0 * EE) : (sf + (m0 - QQ) * EE);
    float acc[2][4] = {{0,0,0,0},{0,0,0,0}};
    mm_tile(Xrow, EE, Wn1 + n0, HH, Xs, Ws, acc);
    const int tx = tid & 15, ty = tid >> 4;
    #pragma unroll
    for (int im = 0; im < 2; im++) {
        int m = m0 + ty + (im << 4);
        int n = n0 + (tx << 2);
        float4 o;
        o.x = fmaxf(acc[im][0] + bn1[n + 0], 0.f);
        o.y = fmaxf(acc[im][1] + bn1[n + 1], 0.f);
        o.z = fmaxf(acc[im][2] + bn1[n + 2], 0.f);
        o.w = fmaxf(acc[im][3] + bn1[n + 3], 0.f);
        *(float4*)&X1[m * HH + n] = o;
    }
}

// ---------------------------------------------------------------------------
// Plain gemm: C = X @ W (+bias). grid (N/64, M/32).
// ---------------------------------------------------------------------------
__global__ __launch_bounds__(256) void gemm_k(const float* __restrict__ X,
                                              const float* __restrict__ W,
                                              const float* __restrict__ bias,
                                              float* __restrict__ C,
                                              int K) {
    GEMM_SHARED;
    const int tid = threadIdx.x;
    const int m0 = blockIdx.y << 5;
    const int n0 = blockIdx.x << 6;
    float acc[2][4] = {{0,0,0,0},{0,0,0,0}};
    mm_tile(X + m0 * K, K, W + n0, HH, Xs, Ws, acc);
    const int tx = tid & 15, ty = tid >> 4;
    #pragma unroll
    for (int im = 0; im < 2; im++) {
        int m = m0 + ty + (im << 4);
        int n = n0 + (tx << 2);
        float4 o;
        float bx = bias ? bias[n + 0] : 0.f;
        float by = bias ? bias[n + 1] : 0.f;
        float bz = bias ? bias[n + 2] : 0.f;
        float bw = bias ? bias[n + 3] : 0.f;
        o.x = acc[im][0] + bx; o.y = acc[im][1] + by;
        o.z = acc[im][2] + bz; o.w = acc[im][3] + bw;
        *(float4*)&C[m * HH + n] = o;
    }
}

// ---------------------------------------------------------------------------
// ab: A = s@W1a, B = s@W1b in one launch. grid (8, 16); bx<4 -> A, else B.
// ---------------------------------------------------------------------------
__global__ __launch_bounds__(256) void ab_k(const float* __restrict__ s,
                                            const float* __restrict__ W1,  // Wm1[t], (512,256)
                                            float* __restrict__ A,
                                            float* __restrict__ B) {
    GEMM_SHARED;
    const int tid = threadIdx.x;
    const int m0 = blockIdx.y << 5;
    int nt = blockIdx.x;
    const float* W = W1;
    float* C = A;
    if (nt >= 4) { nt -= 4; W = W1 + HH * HH; C = B; }
    const int n0 = nt << 6;
    float acc[2][4] = {{0,0,0,0},{0,0,0,0}};
    mm_tile(s + m0 * HH, HH, W + n0, HH, Xs, Ws, acc);
    const int tx = tid & 15, ty = tid >> 4;
    #pragma unroll
    for (int im = 0; im < 2; im++) {
        int m = m0 + ty + (im << 4);
        int n = n0 + (tx << 2);
        float4 o = { acc[im][0], acc[im][1], acc[im][2], acc[im][3] };
        *(float4*)&C[m * HH + n] = o;
    }
}

// ---------------------------------------------------------------------------
// hsum[i][h] = sum_{j in class(i), j != i} relu(A[i][h] + bm1[h] + B[j][h])
// Uses per-class member lists: ~32 iterations instead of 512.
// ---------------------------------------------------------------------------
__global__ __launch_bounds__(256) void hsum_k(const float* __restrict__ A,
                                              const float* __restrict__ B,
                                              const int* __restrict__ y,
                                              const int* __restrict__ cls_cnt,
                                              const int* __restrict__ cls_list,
                                              const float* __restrict__ bm1t,
                                              float* __restrict__ hsum) {
    __shared__ int lst[SS];
    __shared__ int info[2];
    const int i = blockIdx.x;
    const int h = threadIdx.x;
    if (h == 0) { int yi = y[i]; info[0] = yi; info[1] = cls_cnt[yi]; }
    __syncthreads();
    const int cnt = info[1];
    const int* Lp = cls_list + info[0] * SS;
    for (int m = h; m < cnt; m += 256) lst[m] = Lp[m];
    __syncthreads();
    const float a = A[i * HH + h] + bm1t[h];
    float acc = 0.f;
    #pragma unroll 4
    for (int m = 0; m < cnt; m++) {
        int j = lst[m];
        float v = fmaxf(a + B[j * HH + h], 0.f);
        acc += (j == i) ? 0.f : v;
    }
    hsum[i * HH + h] = acc;
}

// ---------------------------------------------------------------------------
// gagg: s += (hsum@W2 + cnt*bm2) * invden   (gemm + fused aggregate epilogue)
// grid (4, 16).
// ---------------------------------------------------------------------------
__global__ __launch_bounds__(256) void gagg_k(const float* __restrict__ hsum,
                                              const float* __restrict__ W2,
                                              const float* __restrict__ bm2t,
                                              const float* __restrict__ cntf,
                                              const float* __restrict__ invd,
                                              float* __restrict__ s) {
    GEMM_SHARED;
    const int tid = threadIdx.x;
    const int m0 = blockIdx.y << 5;
    const int n0 = blockIdx.x << 6;
    float acc[2][4] = {{0,0,0,0},{0,0,0,0}};
    mm_tile(hsum + m0 * HH, HH, W2 + n0, HH, Xs, Ws, acc);
    const int tx = tid & 15, ty = tid >> 4;
    #pragma unroll
    for (int im = 0; im < 2; im++) {
        int m = m0 + ty + (im << 4);
        int n = n0 + (tx << 2);
        float ci = cntf[m], di = invd[m];
        float* sp = &s[m * HH + n];
        float4 sv = *(float4*)sp;
        float4 o;
        o.x = sv.x + (acc[im][0] + ci * bm2t[n + 0]) * di;
        o.y = sv.y + (acc[im][1] + ci * bm2t[n + 1]) * di;
        o.z = sv.z + (acc[im][2] + ci * bm2t[n + 2]) * di;
        o.w = sv.w + (acc[im][3] + ci * bm2t[n + 3]) * di;
        *(float4*)sp = o;
    }
}

// ---------------------------------------------------------------------------
// rel: hq = q@Wr1a (by<32);  hsT[h][j] = (s@Wr1b)[j][h] + br1[h] (by>=32,
// transposed store kills the separate transpose kernel). grid (4, 48).
// ---------------------------------------------------------------------------
__global__ __launch_bounds__(256) void rel_k(const float* __restrict__ q,
                                             const float* __restrict__ s,
                                             const float* __restrict__ Wr1,
                                             const float* __restrict__ br1,
                                             float* __restrict__ hq,
                                             float* __restrict__ hsT) {
    GEMM_SHARED;
    const int tid = threadIdx.x;
    const int n0 = blockIdx.x << 6;
    const int tx = tid & 15, ty = tid >> 4;
    float acc[2][4] = {{0,0,0,0},{0,0,0,0}};
    if (blockIdx.y < 32) {
        const int m0 = blockIdx.y << 5;
        mm_tile(q + m0 * HH, HH, Wr1 + n0, HH, Xs, Ws, acc);
        #pragma unroll
        for (int im = 0; im < 2; im++) {
            int m = m0 + ty + (im << 4);
            int n = n0 + (tx << 2);
            float4 o = { acc[im][0], acc[im][1], acc[im][2], acc[im][3] };
            *(float4*)&hq[m * HH + n] = o;
        }
    } else {
        const int m0 = (blockIdx.y - 32) << 5;
        mm_tile(s + m0 * HH, HH, Wr1 + HH * HH + n0, HH, Xs, Ws, acc);
        #pragma unroll
        for (int im = 0; im < 2; im++) {
            int m = m0 + ty + (im << 4);
            #pragma unroll
            for (int c = 0; c < 4; c++) {
                int n = n0 + (tx << 2) + c;
                hsT[n * SS + m] = acc[im][c] + br1[n];
            }
        }
    }
}

// ---------------------------------------------------------------------------
// scores[i][j] = sum_h relu(hq[i][h] + hsT[h][j]) * wr2[h] + br2
// grid (Q/8, S/256), 256 threads; 8 i-rows per block; hsT value prefetched.
// ---------------------------------------------------------------------------
__global__ __launch_bounds__(256) void scores_k(const float* __restrict__ hq,
                                                const float* __restrict__ hsT,
                                                const float* __restrict__ wr2,
                                                const float* __restrict__ br2,
                                                float* __restrict__ out) {
    __shared__ float hqs[8][HH];
    __shared__ float w2s[HH];
    const int tid = threadIdx.x;
    const int i0 = blockIdx.x << 3;
    const int j  = (blockIdx.y << 8) + tid;
    w2s[tid] = wr2[tid];
    #pragma unroll
    for (int ii = 0; ii < 8; ii++) hqs[ii][tid] = hq[(i0 + ii) * HH + tid];
    __syncthreads();
    float acc[8] = {0,0,0,0,0,0,0,0};
    float vnext = hsT[j];
    #pragma unroll 4
    for (int h = 0; h < HH; h++) {
        float v = vnext;
        if (h + 1 < HH) vnext = hsT[(h + 1) * SS + j];
        float w = w2s[h];
        #pragma unroll
        for (int ii = 0; ii < 8; ii++) {
            acc[ii] += fmaxf(v + hqs[ii][h], 0.f) * w;
        }
    }
    float b2 = br2[0];
    #pragma unroll
    for (int ii = 0; ii < 8; ii++)
        out[(i0 + ii) * SS + j] = acc[ii] + b2;
}

extern "C" void kernel_launch(void* const* d_in, const int* in_sizes, int n_in,
                              void* d_out, int out_size, void* d_ws, size_t ws_size,
                              hipStream_t stream) {
    const float* qf  = (const float*)d_in[0];
    const float* sf  = (const float*)d_in[1];
    const int*   y   = (const int*)d_in[2];
    const float* Wn1 = (const float*)d_in[3];
    const float* bn1 = (const float*)d_in[4];
    const float* Wn2 = (const float*)d_in[5];
    const float* bn2 = (const float*)d_in[6];
    const float* Wm1 = (const float*)d_in[7];
    const float* bm1 = (const float*)d_in[8];
    const float* Wm2 = (const float*)d_in[9];
    const float* bm2 = (const float*)d_in[10];
    const float* Wr1 = (const float*)d_in[11];
    const float* br1 = (const float*)d_in[12];
    const float* wr2 = (const float*)d_in[13];
    const float* br2 = (const float*)d_in[14];
    float* out = (float*)d_out;

    float* F    = (float*)d_ws;
    float* X1   = F + 0;             // 1536*256 (dead after enc2)
    float* QS   = F + 393216;        // 1536*256
    float* q    = QS;                // 1024*256
    float* s    = QS + QQ * HH;      // 512*256
    float* A    = F + 786432;        // 512*256
    float* Bm   = F + 917504;        // 512*256
    float* hsum = F + 1048576;       // 512*256
    float* hq   = F + 0;             // 1024*256 (reuses dead X1)
    float* hsT  = F + 262144;        // 256*512  (inside dead X1)
    float* cntf = F + 1179648;       // 512
    float* invd = F + 1180160;       // 512
    int*  icls  = (int*)(F + 1180672);
    int*  cls_cnt  = icls;           // 16
    int*  cls_list = icls + 16;      // 16*512

    // encoder (+ fused mask statistics in the extra block row)
    enc1_k<<<dim3(4, 49), 256, 0, stream>>>(qf, sf, Wn1, bn1, X1,
                                            y, cntf, invd, cls_cnt, cls_list);
    gemm_k<<<dim3(4, 48), 256, 0, stream>>>(X1, Wn2, bn2, QS, HH);

    // message passing (masked sum factored before the Wm2 matmul)
    for (int t = 0; t < NSTEPS; t++) {
        const float* W1t = Wm1 + t * 2 * HH * HH;
        const float* b1t = bm1 + t * HH;
        const float* W2t = Wm2 + t * HH * HH;
        const float* b2t = bm2 + t * HH;
        ab_k<<<dim3(8, 16), 256, 0, stream>>>(s, W1t, A, Bm);
        hsum_k<<<SS, 256, 0, stream>>>(A, Bm, y, cls_cnt, cls_list, b1t, hsum);
        gagg_k<<<dim3(4, 16), 256, 0, stream>>>(hsum, W2t, b2t, cntf, invd, s);
    }

    // relation head
    rel_k<<<dim3(4, 48), 256, 0, stream>>>(q, s, Wr1, br1, hq, hsT);
    scores_k<<<dim3(QQ / 8, SS / 256), 256, 0, stream>>>(hq, hsT, wr2, br2, out);
}

// Round 5
// 211.633 us; speedup vs baseline: 2.4960x; 1.1213x over previous
//
#include <hip/hip_runtime.h>

#define EE 512
#define HH 256
#define QQ 1024
#define SS 512
#define NSTEPS 3

// ---------------------------------------------------------------------------
// 32x64 GEMM tile engine v2: 256 threads, BK=32, register-prefetch double
// buffering. X-tile stored K-MAJOR (Xs[k][m], stride 66) so the inner loop is
// ds_read_b64 (2 consecutive rows) + ds_read_b128 (4 cols) per kk.
// acc[2][4]: rows m0+2*ty{+0,1}, cols n0+4*tx..+3.
// Stride 66 (even, !=0 mod4-multiple-of-8) -> staging writes 2-way max (free).
// ---------------------------------------------------------------------------
#define GEMM_SHARED __shared__ float Xs[32][66]; __shared__ float Ws[32][68]

__device__ __forceinline__ void mm_tile(const float* __restrict__ Xrow, int K,
                                        const float* __restrict__ Wcol, int N,
                                        float (*Xs)[66], float (*Ws)[68],
                                        float acc[2][4]) {
    const int tid = threadIdx.x;
    const int r   = tid >> 3;          // 0..31
    const int c4  = (tid & 7) << 2;    // X k-chunk
    const int c8  = (tid & 7) << 3;    // W n-chunk
    const int tx  = tid & 15;
    const int ty2 = (tid >> 4) << 1;   // row pair base

    float4 vx  = *(const float4*)&Xrow[r * K + c4];
    float4 vw0 = *(const float4*)&Wcol[r * N + c8];
    float4 vw1 = *(const float4*)&Wcol[r * N + c8 + 4];

    for (int k0 = 0; k0 < K; k0 += 32) {
        Xs[c4 + 0][r] = vx.x;          // k-major scatter (2-way conflicts max)
        Xs[c4 + 1][r] = vx.y;
        Xs[c4 + 2][r] = vx.z;
        Xs[c4 + 3][r] = vx.w;
        *(float4*)&Ws[r][c8]     = vw0;
        *(float4*)&Ws[r][c8 + 4] = vw1;
        __syncthreads();
        if (k0 + 32 < K) {   // prefetch next K-tile while FMAs run
            vx  = *(const float4*)&Xrow[r * K + k0 + 32 + c4];
            vw0 = *(const float4*)&Wcol[(k0 + 32 + r) * N + c8];
            vw1 = *(const float4*)&Wcol[(k0 + 32 + r) * N + c8 + 4];
        }
        #pragma unroll
        for (int kk = 0; kk < 32; kk++) {
            float4 b = *(const float4*)&Ws[kk][tx << 2];
            float2 a = *(const float2*)&Xs[kk][ty2];
            acc[0][0] += a.x * b.x; acc[0][1] += a.x * b.y;
            acc[0][2] += a.x * b.z; acc[0][3] += a.x * b.w;
            acc[1][0] += a.y * b.x; acc[1][1] += a.y * b.y;
            acc[1][2] += a.y * b.z; acc[1][3] += a.y * b.w;
        }
        __syncthreads();
    }
}

// ---------------------------------------------------------------------------
// enc1: [q;s] @ Wn1 + bn1, relu -> X1 (1536 x 256). K=512.
// grid (4, 49): by==48 is the mask-statistics block (class lists, counts).
// ---------------------------------------------------------------------------
__global__ __launch_bounds__(256) void enc1_k(const float* __restrict__ qf,
                                              const float* __restrict__ sf,
                                              const float* __restrict__ Wn1,
                                              const float* __restrict__ bn1,
                                              float* __restrict__ X1,
                                              const int* __restrict__ y,
                                              float* __restrict__ cntf,
                                              float* __restrict__ invd,
                                              int* __restrict__ cls_cnt,
                                              int* __restrict__ cls_list) {
    GEMM_SHARED;
    const int tid = threadIdx.x;
    if (blockIdx.y == 48) {                  // mask statistics
        if (blockIdx.x != 0) return;
        __shared__ int lc[16];
        if (tid < 16) lc[tid] = 0;
        __syncthreads();
        for (int i = tid; i < SS; i += 256) {
            int c = y[i];
            int slot = atomicAdd(&lc[c], 1);
            cls_list[c * SS + slot] = i;
        }
        __syncthreads();
        if (tid < 16) cls_cnt[tid] = lc[tid];
        for (int i = tid; i < SS; i += 256) {
            float n = (float)(lc[y[i]] - 1);
            cntf[i] = n;
            invd[i] = 1.f / fmaxf(n, 1.f);
        }
        return;
    }
    const int m0 = blockIdx.y << 5;
    const int n0 = blockIdx.x << 6;
    const float* Xrow = (m0 < QQ) ? (qf + m0 * EE) : (sf + (m0 - QQ) * EE);
    float acc[2][4] = {{0,0,0,0},{0,0,0,0}};
    mm_tile(Xrow, EE, Wn1 + n0, HH, Xs, Ws, acc);
    const int tx = tid & 15, ty2 = (tid >> 4) << 1;
    #pragma unroll
    for (int rr = 0; rr < 2; rr++) {
        int m = m0 + ty2 + rr;
        int n = n0 + (tx << 2);
        float4 o;
        o.x = fmaxf(acc[rr][0] + bn1[n + 0], 0.f);
        o.y = fmaxf(acc[rr][1] + bn1[n + 1], 0.f);
        o.z = fmaxf(acc[rr][2] + bn1[n + 2], 0.f);
        o.w = fmaxf(acc[rr][3] + bn1[n + 3], 0.f);
        *(float4*)&X1[m * HH + n] = o;
    }
}

// ---------------------------------------------------------------------------
// Plain gemm: C = X @ W (+bias). grid (N/64, M/32).
// ---------------------------------------------------------------------------
__global__ __launch_bounds__(256) void gemm_k(const float* __restrict__ X,
                                              const float* __restrict__ W,
                                              const float* __restrict__ bias,
                                              float* __restrict__ C,
                                              int K) {
    GEMM_SHARED;
    const int tid = threadIdx.x;
    const int m0 = blockIdx.y << 5;
    const int n0 = blockIdx.x << 6;
    float acc[2][4] = {{0,0,0,0},{0,0,0,0}};
    mm_tile(X + m0 * K, K, W + n0, HH, Xs, Ws, acc);
    const int tx = tid & 15, ty2 = (tid >> 4) << 1;
    #pragma unroll
    for (int rr = 0; rr < 2; rr++) {
        int m = m0 + ty2 + rr;
        int n = n0 + (tx << 2);
        float bx = bias ? bias[n + 0] : 0.f;
        float by = bias ? bias[n + 1] : 0.f;
        float bz = bias ? bias[n + 2] : 0.f;
        float bw = bias ? bias[n + 3] : 0.f;
        float4 o;
        o.x = acc[rr][0] + bx; o.y = acc[rr][1] + by;
        o.z = acc[rr][2] + bz; o.w = acc[rr][3] + bw;
        *(float4*)&C[m * HH + n] = o;
    }
}

// ---------------------------------------------------------------------------
// ab: A = s@W1a, B = s@W1b in one launch. grid (8, 16); bx<4 -> A, else B.
// ---------------------------------------------------------------------------
__global__ __launch_bounds__(256) void ab_k(const float* __restrict__ s,
                                            const float* __restrict__ W1,  // Wm1[t], (512,256)
                                            float* __restrict__ A,
                                            float* __restrict__ B) {
    GEMM_SHARED;
    const int tid = threadIdx.x;
    const int m0 = blockIdx.y << 5;
    int nt = blockIdx.x;
    const float* W = W1;
    float* C = A;
    if (nt >= 4) { nt -= 4; W = W1 + HH * HH; C = B; }
    const int n0 = nt << 6;
    float acc[2][4] = {{0,0,0,0},{0,0,0,0}};
    mm_tile(s + m0 * HH, HH, W + n0, HH, Xs, Ws, acc);
    const int tx = tid & 15, ty2 = (tid >> 4) << 1;
    #pragma unroll
    for (int rr = 0; rr < 2; rr++) {
        int m = m0 + ty2 + rr;
        int n = n0 + (tx << 2);
        float4 o = { acc[rr][0], acc[rr][1], acc[rr][2], acc[rr][3] };
        *(float4*)&C[m * HH + n] = o;
    }
}

// ---------------------------------------------------------------------------
// hsum[i][h] = sum_{j in class(i), j != i} relu(A[i][h] + bm1[h] + B[j][h])
// Per-class member lists (~32 iters); 4-deep load prefetch.
// ---------------------------------------------------------------------------
__global__ __launch_bounds__(256) void hsum_k(const float* __restrict__ A,
                                              const float* __restrict__ B,
                                              const int* __restrict__ y,
                                              const int* __restrict__ cls_cnt,
                                              const int* __restrict__ cls_list,
                                              const float* __restrict__ bm1t,
                                              float* __restrict__ hsum) {
    __shared__ int lst[SS];
    __shared__ int info[2];
    const int i = blockIdx.x;
    const int h = threadIdx.x;
    if (h == 0) { int yi = y[i]; info[0] = yi; info[1] = cls_cnt[yi]; }
    __syncthreads();
    const int cnt = info[1];
    const int* Lp = cls_list + info[0] * SS;
    for (int m = h; m < cnt; m += 256) lst[m] = Lp[m];
    __syncthreads();
    const float a = A[i * HH + h] + bm1t[h];
    float acc = 0.f;
    int m = 0;
    for (; m + 4 <= cnt; m += 4) {            // 4 loads in flight
        float v0 = B[lst[m + 0] * HH + h];
        float v1 = B[lst[m + 1] * HH + h];
        float v2 = B[lst[m + 2] * HH + h];
        float v3 = B[lst[m + 3] * HH + h];
        acc += fmaxf(a + v0, 0.f) + fmaxf(a + v1, 0.f)
             + fmaxf(a + v2, 0.f) + fmaxf(a + v3, 0.f);
    }
    for (; m < cnt; m++) acc += fmaxf(a + B[lst[m] * HH + h], 0.f);
    // loop included j == i (same class by definition): subtract self term
    acc -= fmaxf(a + B[i * HH + h], 0.f);
    hsum[i * HH + h] = acc;
}

// ---------------------------------------------------------------------------
// gagg: s += (hsum@W2 + cnt*bm2) * invden   (gemm + fused aggregate epilogue)
// grid (4, 16).
// ---------------------------------------------------------------------------
__global__ __launch_bounds__(256) void gagg_k(const float* __restrict__ hsum,
                                              const float* __restrict__ W2,
                                              const float* __restrict__ bm2t,
                                              const float* __restrict__ cntf,
                                              const float* __restrict__ invd,
                                              float* __restrict__ s) {
    GEMM_SHARED;
    const int tid = threadIdx.x;
    const int m0 = blockIdx.y << 5;
    const int n0 = blockIdx.x << 6;
    float acc[2][4] = {{0,0,0,0},{0,0,0,0}};
    mm_tile(hsum + m0 * HH, HH, W2 + n0, HH, Xs, Ws, acc);
    const int tx = tid & 15, ty2 = (tid >> 4) << 1;
    #pragma unroll
    for (int rr = 0; rr < 2; rr++) {
        int m = m0 + ty2 + rr;
        int n = n0 + (tx << 2);
        float ci = cntf[m], di = invd[m];
        float* sp = &s[m * HH + n];
        float4 sv = *(float4*)sp;
        float4 o;
        o.x = sv.x + (acc[rr][0] + ci * bm2t[n + 0]) * di;
        o.y = sv.y + (acc[rr][1] + ci * bm2t[n + 1]) * di;
        o.z = sv.z + (acc[rr][2] + ci * bm2t[n + 2]) * di;
        o.w = sv.w + (acc[rr][3] + ci * bm2t[n + 3]) * di;
        *(float4*)sp = o;
    }
}

// ---------------------------------------------------------------------------
// rel: hq = q@Wr1a (by<32);  hsT[h][j] = (s@Wr1b)[j][h] + br1[h] (by>=32).
// grid (4, 48).
// ---------------------------------------------------------------------------
__global__ __launch_bounds__(256) void rel_k(const float* __restrict__ q,
                                             const float* __restrict__ s,
                                             const float* __restrict__ Wr1,
                                             const float* __restrict__ br1,
                                             float* __restrict__ hq,
                                             float* __restrict__ hsT) {
    GEMM_SHARED;
    const int tid = threadIdx.x;
    const int n0 = blockIdx.x << 6;
    const int tx = tid & 15, ty2 = (tid >> 4) << 1;
    float acc[2][4] = {{0,0,0,0},{0,0,0,0}};
    if (blockIdx.y < 32) {
        const int m0 = blockIdx.y << 5;
        mm_tile(q + m0 * HH, HH, Wr1 + n0, HH, Xs, Ws, acc);
        #pragma unroll
        for (int rr = 0; rr < 2; rr++) {
            int m = m0 + ty2 + rr;
            int n = n0 + (tx << 2);
            float4 o = { acc[rr][0], acc[rr][1], acc[rr][2], acc[rr][3] };
            *(float4*)&hq[m * HH + n] = o;
        }
    } else {
        const int m0 = (blockIdx.y - 32) << 5;
        mm_tile(s + m0 * HH, HH, Wr1 + HH * HH + n0, HH, Xs, Ws, acc);
        #pragma unroll
        for (int rr = 0; rr < 2; rr++) {
            int m = m0 + ty2 + rr;
            #pragma unroll
            for (int c = 0; c < 4; c++) {
                int n = n0 + (tx << 2) + c;
                hsT[n * SS + m] = acc[rr][c] + br1[n];
            }
        }
    }
}

// ---------------------------------------------------------------------------
// scores[i][j] = sum_h relu(hq[i][h] + hsT[h][j]) * wr2[h] + br2
// grid (Q/4, S/256) = 512 blocks (2/CU); h in chunks of 8 with 8 loads in
// flight; hq/wr2 from LDS via b128. br1 already folded into hsT.
// ---------------------------------------------------------------------------
__global__ __launch_bounds__(256) void scores_k(const float* __restrict__ hq,
                                                const float* __restrict__ hsT,
                                                const float* __restrict__ wr2,
                                                const float* __restrict__ br2,
                                                float* __restrict__ out) {
    __shared__ float hqs[4][HH];
    __shared__ float w2s[HH];
    const int tid = threadIdx.x;
    const int i0 = blockIdx.x << 2;
    const int j  = (blockIdx.y << 8) + tid;
    w2s[tid] = wr2[tid];
    #pragma unroll
    for (int ii = 0; ii < 4; ii++) hqs[ii][tid] = hq[(i0 + ii) * HH + tid];
    __syncthreads();
    float acc[4] = {0, 0, 0, 0};
    for (int h0 = 0; h0 < HH; h0 += 8) {
        float v[8];
        #pragma unroll
        for (int u = 0; u < 8; u++) v[u] = hsT[(h0 + u) * SS + j];  // 8 in flight
        float4 w0 = *(const float4*)&w2s[h0];
        float4 w1 = *(const float4*)&w2s[h0 + 4];
        #pragma unroll
        for (int ii = 0; ii < 4; ii++) {
            float4 a0 = *(const float4*)&hqs[ii][h0];
            float4 a1 = *(const float4*)&hqs[ii][h0 + 4];
            acc[ii] += fmaxf(v[0] + a0.x, 0.f) * w0.x
                     + fmaxf(v[1] + a0.y, 0.f) * w0.y
                     + fmaxf(v[2] + a0.z, 0.f) * w0.z
                     + fmaxf(v[3] + a0.w, 0.f) * w0.w
                     + fmaxf(v[4] + a1.x, 0.f) * w1.x
                     + fmaxf(v[5] + a1.y, 0.f) * w1.y
                     + fmaxf(v[6] + a1.z, 0.f) * w1.z
                     + fmaxf(v[7] + a1.w, 0.f) * w1.w;
        }
    }
    float b2 = br2[0];
    #pragma unroll
    for (int ii = 0; ii < 4; ii++)
        out[(i0 + ii) * SS + j] = acc[ii] + b2;
}

extern "C" void kernel_launch(void* const* d_in, const int* in_sizes, int n_in,
                              void* d_out, int out_size, void* d_ws, size_t ws_size,
                              hipStream_t stream) {
    const float* qf  = (const float*)d_in[0];
    const float* sf  = (const float*)d_in[1];
    const int*   y   = (const int*)d_in[2];
    const float* Wn1 = (const float*)d_in[3];
    const float* bn1 = (const float*)d_in[4];
    const float* Wn2 = (const float*)d_in[5];
    const float* bn2 = (const float*)d_in[6];
    const float* Wm1 = (const float*)d_in[7];
    const float* bm1 = (const float*)d_in[8];
    const float* Wm2 = (const float*)d_in[9];
    const float* bm2 = (const float*)d_in[10];
    const float* Wr1 = (const float*)d_in[11];
    const float* br1 = (const float*)d_in[12];
    const float* wr2 = (const float*)d_in[13];
    const float* br2 = (const float*)d_in[14];
    float* out = (float*)d_out;

    float* F    = (float*)d_ws;
    float* X1   = F + 0;             // 1536*256 (dead after enc2)
    float* QS   = F + 393216;        // 1536*256
    float* q    = QS;                // 1024*256
    float* s    = QS + QQ * HH;      // 512*256
    float* A    = F + 786432;        // 512*256
    float* Bm   = F + 917504;        // 512*256
    float* hsum = F + 1048576;       // 512*256
    float* hq   = F + 0;             // 1024*256 (reuses dead X1)
    float* hsT  = F + 262144;        // 256*512  (inside dead X1)
    float* cntf = F + 1179648;       // 512
    float* invd = F + 1180160;       // 512
    int*  icls  = (int*)(F + 1180672);
    int*  cls_cnt  = icls;           // 16
    int*  cls_list = icls + 16;      // 16*512

    // encoder (+ fused mask statistics in the extra block row)
    enc1_k<<<dim3(4, 49), 256, 0, stream>>>(qf, sf, Wn1, bn1, X1,
                                            y, cntf, invd, cls_cnt, cls_list);
    gemm_k<<<dim3(4, 48), 256, 0, stream>>>(X1, Wn2, bn2, QS, HH);

    // message passing (masked sum factored before the Wm2 matmul)
    for (int t = 0; t < NSTEPS; t++) {
        const float* W1t = Wm1 + t * 2 * HH * HH;
        const float* b1t = bm1 + t * HH;
        const float* W2t = Wm2 + t * HH * HH;
        const float* b2t = bm2 + t * HH;
        ab_k<<<dim3(8, 16), 256, 0, stream>>>(s, W1t, A, Bm);
        hsum_k<<<SS, 256, 0, stream>>>(A, Bm, y, cls_cnt, cls_list, b1t, hsum);
        gagg_k<<<dim3(4, 16), 256, 0, stream>>>(hsum, W2t, b2t, cntf, invd, s);
    }

    // relation head
    rel_k<<<dim3(4, 48), 256, 0, stream>>>(q, s, Wr1, br1, hq, hsT);
    scores_k<<<dim3(QQ / 4, SS / 256), 256, 0, stream>>>(hq, hsT, wr2, br2, out);
}